// Round 15
// baseline (86.178 us; speedup 1.0000x reference)
//
#include <hip/hip_runtime.h>
#include <stdint.h>

typedef unsigned int uint32;
typedef unsigned long long u64;
typedef short bf16x8 __attribute__((ext_vector_type(8)));
typedef float f32x4 __attribute__((ext_vector_type(4)));

// fp32 -> bf16 bits, round-to-nearest-even
__device__ __forceinline__ unsigned short f2bf(float f) {
  uint32 u = __builtin_bit_cast(uint32, f);
  u += 0x7FFFu + ((u >> 16) & 1u);
  return (unsigned short)(u >> 16);
}

// async global->LDS DMA, 16B per lane; LDS dest = uniform base + lane*16 (HW)
__device__ __forceinline__ void gload_lds16(const void* g, void* l) {
  __builtin_amdgcn_global_load_lds(
      (const __attribute__((address_space(1))) void*)g,
      (__attribute__((address_space(3))) void*)l, 16, 0, 0);
}

// ---------------------------------------------------------------------------
// K1: h = X*W (16384x128 @ 128x64), e_src/e_dst = h.a, store
//   hTt : bf16, k-blocked layout [B][i>>3][d][i&7]  (256KB/batch)
//   E1 = exp(e_dst), E2 = exp(0.2 e_dst)   (per j)
//   ET = exp(-e_src), G = exp(0.8 e_src)   (per i)
// ---------------------------------------------------------------------------
__global__ __launch_bounds__(256) void k1_h_e(
    const float* __restrict__ X, const float* __restrict__ W,
    const float* __restrict__ A, const float* __restrict__ mask,
    unsigned short* __restrict__ hTt,
    float* __restrict__ E1, float* __restrict__ E2,
    float* __restrict__ ET, float* __restrict__ G) {
  __shared__ float WT[64][132];
  const int t = threadIdx.x;
  for (int idx = t; idx < 128 * 64; idx += 256) {
    int k = idx >> 6, d = idx & 63;
    WT[d][k] = W[idx];
  }
  __syncthreads();

  const int dg = t & 15;
  const int rp = t >> 4;
  const int gi0 = blockIdx.x * 32 + rp * 2;

  float a1[4], a2[4];
#pragma unroll
  for (int dd = 0; dd < 4; ++dd) {
    a1[dd] = A[dg + 16 * dd];
    a2[dd] = A[64 + dg + 16 * dd];
  }

  const float4* x0 = (const float4*)(X + (size_t)gi0 * 128);
  const float4* x1 = (const float4*)(X + (size_t)(gi0 + 1) * 128);
  float h0[4] = {0.f, 0.f, 0.f, 0.f}, h1[4] = {0.f, 0.f, 0.f, 0.f};
#pragma unroll 4
  for (int kq = 0; kq < 32; ++kq) {
    const float4 xa = x0[kq], xb = x1[kq];
#pragma unroll
    for (int dd = 0; dd < 4; ++dd) {
      const float4 w4 = *(const float4*)(&WT[dg + 16 * dd][kq * 4]);
      h0[dd] += xa.x * w4.x + xa.y * w4.y + xa.z * w4.z + xa.w * w4.w;
      h1[dd] += xb.x * w4.x + xb.y * w4.y + xb.z * w4.z + xb.w * w4.w;
    }
  }

  float es0 = 0.f, ed0 = 0.f, es1 = 0.f, ed1 = 0.f;
#pragma unroll
  for (int dd = 0; dd < 4; ++dd) {
    es0 += h0[dd] * a1[dd]; ed0 += h0[dd] * a2[dd];
    es1 += h1[dd] * a1[dd]; ed1 += h1[dd] * a2[dd];
  }
#pragma unroll
  for (int m = 1; m < 16; m <<= 1) {
    es0 += __shfl_xor(es0, m, 64);
    ed0 += __shfl_xor(ed0, m, 64);
    es1 += __shfl_xor(es1, m, 64);
    ed1 += __shfl_xor(ed1, m, 64);
  }
  if (dg == 0) {
    ET[gi0] = expf(-es0);      G[gi0] = expf(0.8f * es0);
    E1[gi0] = expf(ed0);       E2[gi0] = expf(0.2f * ed0);
    ET[gi0 + 1] = expf(-es1);  G[gi0 + 1] = expf(0.8f * es1);
    E1[gi0 + 1] = expf(ed1);   E2[gi0 + 1] = expf(0.2f * ed1);
  }

  const float m0 = mask[gi0], m1 = mask[gi0 + 1];
  const int b = gi0 >> 11, i = gi0 & 2047;
  const int ib = i >> 3, io = i & 7;
#pragma unroll
  for (int dd = 0; dd < 4; ++dd) {
    const int d = dg + 16 * dd;
    const uint32 lo = f2bf(h0[dd] * m0);
    const uint32 hi = f2bf(h1[dd] * m1);
    *(uint32*)(hTt + ((size_t)b << 17) + (ib << 9) + (d << 3) + io) = lo | (hi << 16);
  }
}

// ---------------------------------------------------------------------------
// K3: single streaming read of adj (128MB). (unchanged, measured ~26us)
// ---------------------------------------------------------------------------
__global__ __launch_bounds__(256) void k3_stats(
    const int* __restrict__ adj,
    const float* __restrict__ E1, const float* __restrict__ E2,
    const float* __restrict__ ET, const float* __restrict__ G,
    uint32* __restrict__ bitA, uint32* __restrict__ bitB,
    uint32* __restrict__ PP) {
  const int w = threadIdx.x >> 6, lane = threadIdx.x & 63;
  const int gi = blockIdx.x * 4 + w;
  const int b = gi >> 11, i = gi & 2047;
  const float eti = ET[gi];
  const int4* arow = (const int4*)(adj + (size_t)gi * 2048);
  const float4* e1p = (const float4*)(E1 + b * 2048);
  const float4* e2p = (const float4*)(E2 + b * 2048);
  float s1 = 0.f, s2 = 0.f;
#pragma unroll
  for (int jc = 0; jc < 8; ++jc) {
    const int idx = jc * 64 + lane;
    const int4 av = arow[idx];
    const float4 e1 = e1p[idx];
    const float4 e2 = e2p[idx];
    const bool m0 = (av.x == 1), m1b = (av.y == 1), m2 = (av.z == 1), m3 = (av.w == 1);
    const bool q0 = (e1.x > eti), q1 = (e1.y > eti), q2 = (e1.z > eti), q3 = (e1.w > eti);
    s1 += (m0 && q0) ? e1.x : 0.f;   s2 += (m0 && !q0) ? e2.x : 0.f;
    s1 += (m1b && q1) ? e1.y : 0.f;  s2 += (m1b && !q1) ? e2.y : 0.f;
    s1 += (m2 && q2) ? e1.z : 0.f;   s2 += (m2 && !q2) ? e2.z : 0.f;
    s1 += (m3 && q3) ? e1.w : 0.f;   s2 += (m3 && !q3) ? e2.w : 0.f;
    const u64 b0 = __ballot(m0), b1 = __ballot(m1b), b2 = __ballot(m2), b3 = __ballot(m3);
    if (lane < 4) {
      const u64 v = (lane == 0) ? b0 : (lane == 1) ? b1 : (lane == 2) ? b2 : b3;
      const size_t off = (size_t)(b * 32 + jc * 4 + lane) * 2048 + i;
      bitA[off] = (uint32)v;
      bitB[off] = (uint32)(v >> 32);
    }
  }
#pragma unroll
  for (int m = 1; m < 64; m <<= 1) {
    s1 += __shfl_xor(s1, m, 64);
    s2 += __shfl_xor(s2, m, 64);
  }
  if (lane == 0) {
    const float g = G[gi];
    const bool ok = (s1 + s2) > 0.f;
    const float p1 = ok ? 1.f / (s1 + s2 / g) : 0.f;
    const float p2 = ok ? 1.f / (s1 * g + s2) : 0.f;
    PP[gi] = (uint32)f2bf(p1) | ((uint32)f2bf(p2) << 16);
  }
}

// ---------------------------------------------------------------------------
// K4 v8 (DMA-staged B, count-free drain): pe = bit ? max(P1*E1, P2*E2) : 0.
//   Round 14's counted vmcnt(8) raced (mixed DMA + register loads retire
//   out of order). v8 keeps the wave-private LDS double-buffer but uses a
//   COUNT-FREE drain at the TOP of each iteration:
//     { vmcnt(0) -> buf[kt&1] + A(kt) ready | issue DMA(kt+1) -> buf^1 |
//       issue A(kt+1) | compute kt }
//   The freshly-issued DMA has the whole compute of kt (~250cy) to land
//   before the next drain -> latency hidden under compute, not in the MFMA
//   chain. No barriers (wave-private tile). sched_barrier(0) after drain
//   per guide rule #18.
// ---------------------------------------------------------------------------
__global__ __launch_bounds__(256) void k4_fused(
    const unsigned short* __restrict__ hTt,
    const uint32* __restrict__ bitA, const uint32* __restrict__ bitB,
    const float* __restrict__ E1, const float* __restrict__ E2,
    const uint32* __restrict__ PP, float* __restrict__ out) {
  __shared__ unsigned short tile[4][2][2048];  // [wave][buf][4KB tile]
  __shared__ float sAcc[3][16][68];
  const int t = threadIdx.x;
  const int w = t >> 6, l = t & 63;   // w = K-quarter
  const int bid = blockIdx.x;
  const int b = bid & 7;
  const int jt = bid >> 3;            // 0..127
  const int J0 = jt * 16;
  const int jj = J0 + (l & 15);
  const int kg = l >> 4;

  const float rE1 = E1[b * 2048 + jj];
  const float rE2 = E2[b * 2048 + jj];
  const int widx = ((jj >> 8) << 2) + (jj & 3);
  const size_t rowoff = (size_t)(b * 32 + widx) * 2048;
  const int sh = (jj >> 2) & 63;       // plane select uniform per 16-j tile
  const uint32 maskbit = 1u << (sh & 31);
  const uint32* bp = ((sh >= 32) ? bitB : bitA) + rowoff;
  const uint32* PPb = PP + b * 2048;
  const char* hTtB = (const char*)(hTt + ((size_t)b << 17));

  f32x4 acc[4] = {};

  // ---- prologue: DMA tile(kt=0) into buf 0 + A-side loads for kt=0 ----
  {
    const char* gs = hTtB + (((size_t)(w * 512 >> 3)) << 10) + (l << 4);
    gload_lds16(gs, &tile[w][0][0]);
    gload_lds16(gs + 1024, &tile[w][0][512]);
    gload_lds16(gs + 2048, &tile[w][0][1024]);
    gload_lds16(gs + 3072, &tile[w][0][1536]);
  }
  const int ib0 = w * 512 + kg * 8;
  uint4 bq0 = *(const uint4*)(bp + ib0);
  uint4 bq1 = *(const uint4*)(bp + ib0 + 4);
  uint4 pq0 = *(const uint4*)(PPb + ib0);
  uint4 pq1 = *(const uint4*)(PPb + ib0 + 4);

#pragma unroll
  for (int kt = 0; kt < 16; ++kt) {
    // count-free drain: ALL outstanding VMEM complete -> tile[kt&1] fully
    // written by last iteration's DMA, A(kt) registers valid. Immune to
    // cross-type retirement-order semantics (round-14 bug).
    asm volatile("s_waitcnt vmcnt(0)" ::: "memory");
    __builtin_amdgcn_sched_barrier(0);

    // issue DMA stage kt+1 into buf^1 (wrap addresses on last iter; unused)
    const int i0n = w * 512 + ((kt + 1) & 15) * 32;
    {
      const char* gs = hTtB + (((size_t)(i0n >> 3)) << 10) + (l << 4);
      unsigned short* ld = &tile[w][(kt + 1) & 1][0];
      gload_lds16(gs, ld);
      gload_lds16(gs + 1024, ld + 512);
      gload_lds16(gs + 2048, ld + 1024);
      gload_lds16(gs + 3072, ld + 1536);
    }
    // issue A-side register loads for kt+1 (wrap addresses, branchless)
    const int ni = i0n + kg * 8;
    const uint4 nbq0 = *(const uint4*)(bp + ni);
    const uint4 nbq1 = *(const uint4*)(bp + ni + 4);
    const uint4 npq0 = *(const uint4*)(PPb + ni);
    const uint4 npq1 = *(const uint4*)(PPb + ni + 4);

    // compute kt: pe values from current A-side registers
    auto pv = [&](uint32 dw, uint32 pp) -> uint32 {
      const float p1f = __builtin_bit_cast(float, pp << 16);
      const float p2f = __builtin_bit_cast(float, pp & 0xFFFF0000u);
      const float v = fmaxf(p1f * rE1, p2f * rE2);
      return (dw & maskbit) ? __builtin_bit_cast(uint32, v) : 0u;
    };
    uint32 pe[8];
    pe[0] = pv(bq0.x, pq0.x);
    pe[1] = pv(bq0.y, pq0.y);
    pe[2] = pv(bq0.z, pq0.z);
    pe[3] = pv(bq0.w, pq0.w);
    pe[4] = pv(bq1.x, pq1.x);
    pe[5] = pv(bq1.y, pq1.y);
    pe[6] = pv(bq1.z, pq1.z);
    pe[7] = pv(bq1.w, pq1.w);

    union { uint32 u4[4]; bf16x8 v; } af;
#pragma unroll
    for (int e = 0; e < 4; ++e)  // truncating bf16 pair-pack
      af.u4[e] = (pe[2 * e + 1] & 0xFFFF0000u) | (pe[2 * e] >> 16);

    // B-fragments from LDS (short dependent latency, ds_read_b128)
    const unsigned short* tl = &tile[w][kt & 1][kg * 512];
    const bf16x8 bv0 = *(const bf16x8*)(tl + (((l & 15) + 0) << 3));
    const bf16x8 bv1 = *(const bf16x8*)(tl + (((l & 15) + 16) << 3));
    const bf16x8 bv2 = *(const bf16x8*)(tl + (((l & 15) + 32) << 3));
    const bf16x8 bv3 = *(const bf16x8*)(tl + (((l & 15) + 48) << 3));

    acc[0] = __builtin_amdgcn_mfma_f32_16x16x32_bf16(af.v, bv0, acc[0], 0, 0, 0);
    acc[1] = __builtin_amdgcn_mfma_f32_16x16x32_bf16(af.v, bv1, acc[1], 0, 0, 0);
    acc[2] = __builtin_amdgcn_mfma_f32_16x16x32_bf16(af.v, bv2, acc[2], 0, 0, 0);
    acc[3] = __builtin_amdgcn_mfma_f32_16x16x32_bf16(af.v, bv3, acc[3], 0, 0, 0);

    bq0 = nbq0; bq1 = nbq1; pq0 = npq0; pq1 = npq1;
  }

  // reduce across K-quarters + ELU.  C/D: col = l&15 (d), row = (l>>4)*4+r (j)
  if (w > 0) {
#pragma unroll
    for (int dt = 0; dt < 4; ++dt)
#pragma unroll
      for (int r = 0; r < 4; ++r)
        sAcc[w - 1][(l >> 4) * 4 + r][dt * 16 + (l & 15)] = acc[dt][r];
  }
  __syncthreads();
  if (w == 0) {
    float* outb = out + ((size_t)b << 17);
#pragma unroll
    for (int dt = 0; dt < 4; ++dt) {
#pragma unroll
      for (int r = 0; r < 4; ++r) {
        const int jrow = (l >> 4) * 4 + r;
        const int d = dt * 16 + (l & 15);
        float s = acc[dt][r] + sAcc[0][jrow][d] + sAcc[1][jrow][d] + sAcc[2][jrow][d];
        s = s > 0.f ? s : expm1f(s);
        outb[(size_t)(J0 + jrow) * 64 + d] = s;
      }
    }
  }
}

extern "C" void kernel_launch(void* const* d_in, const int* in_sizes, int n_in,
                              void* d_out, int out_size, void* d_ws, size_t ws_size,
                              hipStream_t stream) {
  const float* X = (const float*)d_in[0];     // [8,2048,128] f32
  const int* adj = (const int*)d_in[1];       // [8,2048,2048] i32
  const float* mask = (const float*)d_in[2];  // [8,2048] f32
  const float* W = (const float*)d_in[3];     // [128,64] f32
  const float* A = (const float*)d_in[4];     // [128,1] f32
  float* out = (float*)d_out;                 // [8,2048,64] f32
  char* ws = (char*)d_ws;

  unsigned short* hTt = (unsigned short*)(ws);  // 2 MB (k-blocked)
  float* E1 = (float*)(ws + 2097152);           // 64 KB each
  float* E2 = (float*)(ws + 2162688);
  float* ET = (float*)(ws + 2228224);
  float* G  = (float*)(ws + 2293760);
  uint32* PP = (uint32*)(ws + 2359296);         // 64 KB
  uint32* bitA = (uint32*)(ws + 2424832);       // 2 MB
  uint32* bitB = (uint32*)(ws + 4521984);       // 2 MB (ends 6619136)

  hipLaunchKernelGGL(k1_h_e, dim3(512), dim3(256), 0, stream, X, W, A, mask, hTt, E1, E2, ET, G);
  hipLaunchKernelGGL(k3_stats, dim3(4096), dim3(256), 0, stream, adj, E1, E2, ET, G, bitA, bitB, PP);
  hipLaunchKernelGGL(k4_fused, dim3(1024), dim3(256), 0, stream, hTt, bitA, bitB, E1, E2, PP, out);
}

// Round 16
// 67.577 us; speedup vs baseline: 1.2753x; 1.2753x over previous
//
#include <hip/hip_runtime.h>
#include <stdint.h>

typedef unsigned int uint32;
typedef unsigned long long u64;
typedef short bf16x8 __attribute__((ext_vector_type(8)));
typedef float f32x4 __attribute__((ext_vector_type(4)));

// fp32 -> bf16 bits, round-to-nearest-even
__device__ __forceinline__ unsigned short f2bf(float f) {
  uint32 u = __builtin_bit_cast(uint32, f);
  u += 0x7FFFu + ((u >> 16) & 1u);
  return (unsigned short)(u >> 16);
}

// ---------------------------------------------------------------------------
// K1: h = X*W (16384x128 @ 128x64), e_src/e_dst = h.a, store
//   hTt : bf16, k-blocked layout [B][i>>3][d][i&7]  (256KB/batch)
//   E1 = exp(e_dst), E2 = exp(0.2 e_dst)   (per j)
//   ET = exp(-e_src), G = exp(0.8 e_src)   (per i)
// ---------------------------------------------------------------------------
__global__ __launch_bounds__(256) void k1_h_e(
    const float* __restrict__ X, const float* __restrict__ W,
    const float* __restrict__ A, const float* __restrict__ mask,
    unsigned short* __restrict__ hTt,
    float* __restrict__ E1, float* __restrict__ E2,
    float* __restrict__ ET, float* __restrict__ G) {
  __shared__ float WT[64][132];
  const int t = threadIdx.x;
  for (int idx = t; idx < 128 * 64; idx += 256) {
    int k = idx >> 6, d = idx & 63;
    WT[d][k] = W[idx];
  }
  __syncthreads();

  const int dg = t & 15;
  const int rp = t >> 4;
  const int gi0 = blockIdx.x * 32 + rp * 2;

  float a1[4], a2[4];
#pragma unroll
  for (int dd = 0; dd < 4; ++dd) {
    a1[dd] = A[dg + 16 * dd];
    a2[dd] = A[64 + dg + 16 * dd];
  }

  const float4* x0 = (const float4*)(X + (size_t)gi0 * 128);
  const float4* x1 = (const float4*)(X + (size_t)(gi0 + 1) * 128);
  float h0[4] = {0.f, 0.f, 0.f, 0.f}, h1[4] = {0.f, 0.f, 0.f, 0.f};
#pragma unroll 4
  for (int kq = 0; kq < 32; ++kq) {
    const float4 xa = x0[kq], xb = x1[kq];
#pragma unroll
    for (int dd = 0; dd < 4; ++dd) {
      const float4 w4 = *(const float4*)(&WT[dg + 16 * dd][kq * 4]);
      h0[dd] += xa.x * w4.x + xa.y * w4.y + xa.z * w4.z + xa.w * w4.w;
      h1[dd] += xb.x * w4.x + xb.y * w4.y + xb.z * w4.z + xb.w * w4.w;
    }
  }

  float es0 = 0.f, ed0 = 0.f, es1 = 0.f, ed1 = 0.f;
#pragma unroll
  for (int dd = 0; dd < 4; ++dd) {
    es0 += h0[dd] * a1[dd]; ed0 += h0[dd] * a2[dd];
    es1 += h1[dd] * a1[dd]; ed1 += h1[dd] * a2[dd];
  }
#pragma unroll
  for (int m = 1; m < 16; m <<= 1) {
    es0 += __shfl_xor(es0, m, 64);
    ed0 += __shfl_xor(ed0, m, 64);
    es1 += __shfl_xor(es1, m, 64);
    ed1 += __shfl_xor(ed1, m, 64);
  }
  if (dg == 0) {
    ET[gi0] = expf(-es0);      G[gi0] = expf(0.8f * es0);
    E1[gi0] = expf(ed0);       E2[gi0] = expf(0.2f * ed0);
    ET[gi0 + 1] = expf(-es1);  G[gi0 + 1] = expf(0.8f * es1);
    E1[gi0 + 1] = expf(ed1);   E2[gi0 + 1] = expf(0.2f * ed1);
  }

  const float m0 = mask[gi0], m1 = mask[gi0 + 1];
  const int b = gi0 >> 11, i = gi0 & 2047;
  const int ib = i >> 3, io = i & 7;
#pragma unroll
  for (int dd = 0; dd < 4; ++dd) {
    const int d = dg + 16 * dd;
    const uint32 lo = f2bf(h0[dd] * m0);
    const uint32 hi = f2bf(h1[dd] * m1);
    *(uint32*)(hTt + ((size_t)b << 17) + (ib << 9) + (d << 3) + io) = lo | (hi << 16);
  }
}

// ---------------------------------------------------------------------------
// K3: single streaming read of adj (128MB). (unchanged, measured ~26us)
// ---------------------------------------------------------------------------
__global__ __launch_bounds__(256) void k3_stats(
    const int* __restrict__ adj,
    const float* __restrict__ E1, const float* __restrict__ E2,
    const float* __restrict__ ET, const float* __restrict__ G,
    uint32* __restrict__ bitA, uint32* __restrict__ bitB,
    uint32* __restrict__ PP) {
  const int w = threadIdx.x >> 6, lane = threadIdx.x & 63;
  const int gi = blockIdx.x * 4 + w;
  const int b = gi >> 11, i = gi & 2047;
  const float eti = ET[gi];
  const int4* arow = (const int4*)(adj + (size_t)gi * 2048);
  const float4* e1p = (const float4*)(E1 + b * 2048);
  const float4* e2p = (const float4*)(E2 + b * 2048);
  float s1 = 0.f, s2 = 0.f;
#pragma unroll
  for (int jc = 0; jc < 8; ++jc) {
    const int idx = jc * 64 + lane;
    const int4 av = arow[idx];
    const float4 e1 = e1p[idx];
    const float4 e2 = e2p[idx];
    const bool m0 = (av.x == 1), m1b = (av.y == 1), m2 = (av.z == 1), m3 = (av.w == 1);
    const bool q0 = (e1.x > eti), q1 = (e1.y > eti), q2 = (e1.z > eti), q3 = (e1.w > eti);
    s1 += (m0 && q0) ? e1.x : 0.f;   s2 += (m0 && !q0) ? e2.x : 0.f;
    s1 += (m1b && q1) ? e1.y : 0.f;  s2 += (m1b && !q1) ? e2.y : 0.f;
    s1 += (m2 && q2) ? e1.z : 0.f;   s2 += (m2 && !q2) ? e2.z : 0.f;
    s1 += (m3 && q3) ? e1.w : 0.f;   s2 += (m3 && !q3) ? e2.w : 0.f;
    const u64 b0 = __ballot(m0), b1 = __ballot(m1b), b2 = __ballot(m2), b3 = __ballot(m3);
    if (lane < 4) {
      const u64 v = (lane == 0) ? b0 : (lane == 1) ? b1 : (lane == 2) ? b2 : b3;
      const size_t off = (size_t)(b * 32 + jc * 4 + lane) * 2048 + i;
      bitA[off] = (uint32)v;
      bitB[off] = (uint32)(v >> 32);
    }
  }
#pragma unroll
  for (int m = 1; m < 64; m <<= 1) {
    s1 += __shfl_xor(s1, m, 64);
    s2 += __shfl_xor(s2, m, 64);
  }
  if (lane == 0) {
    const float g = G[gi];
    const bool ok = (s1 + s2) > 0.f;
    const float p1 = ok ? 1.f / (s1 + s2 / g) : 0.f;
    const float p2 = ok ? 1.f / (s1 * g + s2) : 0.f;
    PP[gi] = (uint32)f2bf(p1) | ((uint32)f2bf(p2) << 16);
  }
}

// ---------------------------------------------------------------------------
// K4 v9 (LDS-hoisted A-side): pe = bit ? max(P1*E1, P2*E2) : 0.
//   The A-side (bits/PP) is staged into LDS ONCE per block as a coalesced
//   40KB burst (4 bit-rows x 2048 i + PP), so the 16-kt main loop reads it
//   via ds_read_b128 (short latency, no L2 queueing) -- removes 2/3 of the
//   per-kt L2 loads from the dependence chain. Row pad +4 dwords: the 16
//   distinct (row,kg) addresses map 2-way max per bank (free, m136).
//   B-side: branchless wrap-address register prefetch (rounds 10/11 safe).
//   LDS reused for the epilogue reduce (sync separates lifetimes). 41KB ->
//   3 blocks/CU. No barriers inside the main loop.
// ---------------------------------------------------------------------------
__global__ __launch_bounds__(256) void k4_fused(
    const unsigned short* __restrict__ hTt,
    const uint32* __restrict__ bitA, const uint32* __restrict__ bitB,
    const float* __restrict__ E1, const float* __restrict__ E2,
    const uint32* __restrict__ PP, float* __restrict__ out) {
  __shared__ __align__(16) char raw[41024];
  uint32* bitsL = (uint32*)raw;            // [4][2052] (+4 pad: bank spread)
  uint32* ppL = (uint32*)(raw + 32832);    // [2048]
  float* sa = (float*)raw;                 // reused post-loop: [3][16][68]

  const int t = threadIdx.x;
  const int w = t >> 6, l = t & 63;   // w = K-quarter
  const int bid = blockIdx.x;
  const int b = bid & 7;
  const int jt = bid >> 3;            // 0..127
  const int J0 = jt * 16;
  const int jj = J0 + (l & 15);
  const int kg = l >> 4;

  const float rE1 = E1[b * 2048 + jj];
  const float rE2 = E2[b * 2048 + jj];
  const int widxBase = (J0 >> 8) << 2;        // jj>>8 uniform in tile
  const int sh = (jj >> 2) & 63;              // plane uniform in tile
  const uint32 maskbit = 1u << (sh & 31);
  const uint32* plane = (sh >= 32) ? bitB : bitA;
  const uint32* rowBase = plane + (size_t)(b * 32 + widxBase) * 2048;
  const uint32* PPb = PP + b * 2048;
  const unsigned short* hTtb = hTt + ((size_t)b << 17);

  // ---- cooperative stage: 4 bit-rows (full i range) + PP, coalesced ----
  for (int idx = t; idx < 2048; idx += 256) {
    const int r = idx >> 9, c = (idx & 511) << 2;
    *(uint4*)&bitsL[r * 2052 + c] = *(const uint4*)(rowBase + (size_t)r * 2048 + c);
  }
  for (int idx = t; idx < 512; idx += 256)
    *(uint4*)&ppL[idx << 2] = *(const uint4*)(PPb + (idx << 2));
  __syncthreads();

  f32x4 acc[4] = {};
  const int arow = (l & 3) * 2052;    // lane's bit-row: widxBase + (jj&3)
  const int lane15_3 = (l & 15) << 3;

  // ---- B-side prologue (kt = 0) ----
  size_t bb = ((size_t)((w * 512) >> 3) + kg) << 9;
  bf16x8 bv0 = *(const bf16x8*)(hTtb + bb + lane15_3);
  bf16x8 bv1 = *(const bf16x8*)(hTtb + bb + lane15_3 + 128);
  bf16x8 bv2 = *(const bf16x8*)(hTtb + bb + lane15_3 + 256);
  bf16x8 bv3 = *(const bf16x8*)(hTtb + bb + lane15_3 + 384);

#pragma unroll
  for (int kt = 0; kt < 16; ++kt) {
    const int ibi = w * 512 + kt * 32 + kg * 8;

    // A-side from LDS (ds_read_b128 x4; 2-way bank max = free)
    const uint4 bq0 = *(const uint4*)&bitsL[arow + ibi];
    const uint4 bq1 = *(const uint4*)&bitsL[arow + ibi + 4];
    const uint4 pq0 = *(const uint4*)&ppL[ibi];
    const uint4 pq1 = *(const uint4*)&ppL[ibi + 4];

    // B-side prefetch kt+1 (branchless wrap on last iter; loaded, unused)
    const int i0n = w * 512 + ((kt + 1) & 15) * 32;
    const size_t nbb = ((size_t)(i0n >> 3) + kg) << 9;
    const bf16x8 nv0 = *(const bf16x8*)(hTtb + nbb + lane15_3);
    const bf16x8 nv1 = *(const bf16x8*)(hTtb + nbb + lane15_3 + 128);
    const bf16x8 nv2 = *(const bf16x8*)(hTtb + nbb + lane15_3 + 256);
    const bf16x8 nv3 = *(const bf16x8*)(hTtb + nbb + lane15_3 + 384);

    auto pv = [&](uint32 dw, uint32 pp) -> uint32 {
      const float p1f = __builtin_bit_cast(float, pp << 16);
      const float p2f = __builtin_bit_cast(float, pp & 0xFFFF0000u);
      const float v = fmaxf(p1f * rE1, p2f * rE2);
      return (dw & maskbit) ? __builtin_bit_cast(uint32, v) : 0u;
    };
    uint32 pe[8];
    pe[0] = pv(bq0.x, pq0.x);
    pe[1] = pv(bq0.y, pq0.y);
    pe[2] = pv(bq0.z, pq0.z);
    pe[3] = pv(bq0.w, pq0.w);
    pe[4] = pv(bq1.x, pq1.x);
    pe[5] = pv(bq1.y, pq1.y);
    pe[6] = pv(bq1.z, pq1.z);
    pe[7] = pv(bq1.w, pq1.w);

    union { uint32 u4[4]; bf16x8 v; } af;
#pragma unroll
    for (int e = 0; e < 4; ++e)  // truncating bf16 pair-pack
      af.u4[e] = (pe[2 * e + 1] & 0xFFFF0000u) | (pe[2 * e] >> 16);

    acc[0] = __builtin_amdgcn_mfma_f32_16x16x32_bf16(af.v, bv0, acc[0], 0, 0, 0);
    acc[1] = __builtin_amdgcn_mfma_f32_16x16x32_bf16(af.v, bv1, acc[1], 0, 0, 0);
    acc[2] = __builtin_amdgcn_mfma_f32_16x16x32_bf16(af.v, bv2, acc[2], 0, 0, 0);
    acc[3] = __builtin_amdgcn_mfma_f32_16x16x32_bf16(af.v, bv3, acc[3], 0, 0, 0);

    bv0 = nv0; bv1 = nv1; bv2 = nv2; bv3 = nv3;
  }

  // ---- epilogue: reuse LDS for cross-wave reduce + ELU ----
  __syncthreads();  // all waves done reading bitsL/ppL
  if (w > 0) {
#pragma unroll
    for (int dt = 0; dt < 4; ++dt)
#pragma unroll
      for (int r = 0; r < 4; ++r)
        sa[(w - 1) * 1088 + ((l >> 4) * 4 + r) * 68 + dt * 16 + (l & 15)] = acc[dt][r];
  }
  __syncthreads();
  if (w == 0) {
    float* outb = out + ((size_t)b << 17);
#pragma unroll
    for (int dt = 0; dt < 4; ++dt) {
#pragma unroll
      for (int r = 0; r < 4; ++r) {
        const int jrow = (l >> 4) * 4 + r;
        const int d = dt * 16 + (l & 15);
        float s = acc[dt][r] + sa[jrow * 68 + d] + sa[1088 + jrow * 68 + d] +
                  sa[2176 + jrow * 68 + d];
        s = s > 0.f ? s : expm1f(s);
        outb[(size_t)(J0 + jrow) * 64 + d] = s;
      }
    }
  }
}

extern "C" void kernel_launch(void* const* d_in, const int* in_sizes, int n_in,
                              void* d_out, int out_size, void* d_ws, size_t ws_size,
                              hipStream_t stream) {
  const float* X = (const float*)d_in[0];     // [8,2048,128] f32
  const int* adj = (const int*)d_in[1];       // [8,2048,2048] i32
  const float* mask = (const float*)d_in[2];  // [8,2048] f32
  const float* W = (const float*)d_in[3];     // [128,64] f32
  const float* A = (const float*)d_in[4];     // [128,1] f32
  float* out = (float*)d_out;                 // [8,2048,64] f32
  char* ws = (char*)d_ws;

  unsigned short* hTt = (unsigned short*)(ws);  // 2 MB (k-blocked)
  float* E1 = (float*)(ws + 2097152);           // 64 KB each
  float* E2 = (float*)(ws + 2162688);
  float* ET = (float*)(ws + 2228224);
  float* G  = (float*)(ws + 2293760);
  uint32* PP = (uint32*)(ws + 2359296);         // 64 KB
  uint32* bitA = (uint32*)(ws + 2424832);       // 2 MB
  uint32* bitB = (uint32*)(ws + 4521984);       // 2 MB (ends 6619136)

  hipLaunchKernelGGL(k1_h_e, dim3(512), dim3(256), 0, stream, X, W, A, mask, hTt, E1, E2, ET, G);
  hipLaunchKernelGGL(k3_stats, dim3(4096), dim3(256), 0, stream, adj, E1, E2, ET, G, bitA, bitB, PP);
  hipLaunchKernelGGL(k4_fused, dim3(1024), dim3(256), 0, stream, hTt, bitA, bitB, E1, E2, PP, out);
}

// Round 17
// 64.126 us; speedup vs baseline: 1.3439x; 1.0538x over previous
//
#include <hip/hip_runtime.h>
#include <stdint.h>

typedef unsigned int uint32;
typedef unsigned long long u64;
typedef short bf16x8 __attribute__((ext_vector_type(8)));
typedef float f32x4 __attribute__((ext_vector_type(4)));

// fp32 -> bf16 bits, round-to-nearest-even
__device__ __forceinline__ unsigned short f2bf(float f) {
  uint32 u = __builtin_bit_cast(uint32, f);
  u += 0x7FFFu + ((u >> 16) & 1u);
  return (unsigned short)(u >> 16);
}

// ---------------------------------------------------------------------------
// K1: h = X*W (16384x128 @ 128x64), e_src/e_dst = h.a, store
//   hTt : bf16, k-blocked layout [B][i>>3][d][i&7]  (256KB/batch)
//   E1 = exp(e_dst), E2 = exp(0.2 e_dst)   (per j)
//   ET = exp(-e_src), G = exp(0.8 e_src)   (per i)
// ---------------------------------------------------------------------------
__global__ __launch_bounds__(256) void k1_h_e(
    const float* __restrict__ X, const float* __restrict__ W,
    const float* __restrict__ A, const float* __restrict__ mask,
    unsigned short* __restrict__ hTt,
    float* __restrict__ E1, float* __restrict__ E2,
    float* __restrict__ ET, float* __restrict__ G) {
  __shared__ float WT[64][132];
  const int t = threadIdx.x;
  for (int idx = t; idx < 128 * 64; idx += 256) {
    int k = idx >> 6, d = idx & 63;
    WT[d][k] = W[idx];
  }
  __syncthreads();

  const int dg = t & 15;
  const int rp = t >> 4;
  const int gi0 = blockIdx.x * 32 + rp * 2;

  float a1[4], a2[4];
#pragma unroll
  for (int dd = 0; dd < 4; ++dd) {
    a1[dd] = A[dg + 16 * dd];
    a2[dd] = A[64 + dg + 16 * dd];
  }

  const float4* x0 = (const float4*)(X + (size_t)gi0 * 128);
  const float4* x1 = (const float4*)(X + (size_t)(gi0 + 1) * 128);
  float h0[4] = {0.f, 0.f, 0.f, 0.f}, h1[4] = {0.f, 0.f, 0.f, 0.f};
#pragma unroll 4
  for (int kq = 0; kq < 32; ++kq) {
    const float4 xa = x0[kq], xb = x1[kq];
#pragma unroll
    for (int dd = 0; dd < 4; ++dd) {
      const float4 w4 = *(const float4*)(&WT[dg + 16 * dd][kq * 4]);
      h0[dd] += xa.x * w4.x + xa.y * w4.y + xa.z * w4.z + xa.w * w4.w;
      h1[dd] += xb.x * w4.x + xb.y * w4.y + xb.z * w4.z + xb.w * w4.w;
    }
  }

  float es0 = 0.f, ed0 = 0.f, es1 = 0.f, ed1 = 0.f;
#pragma unroll
  for (int dd = 0; dd < 4; ++dd) {
    es0 += h0[dd] * a1[dd]; ed0 += h0[dd] * a2[dd];
    es1 += h1[dd] * a1[dd]; ed1 += h1[dd] * a2[dd];
  }
#pragma unroll
  for (int m = 1; m < 16; m <<= 1) {
    es0 += __shfl_xor(es0, m, 64);
    ed0 += __shfl_xor(ed0, m, 64);
    es1 += __shfl_xor(es1, m, 64);
    ed1 += __shfl_xor(ed1, m, 64);
  }
  if (dg == 0) {
    ET[gi0] = expf(-es0);      G[gi0] = expf(0.8f * es0);
    E1[gi0] = expf(ed0);       E2[gi0] = expf(0.2f * ed0);
    ET[gi0 + 1] = expf(-es1);  G[gi0 + 1] = expf(0.8f * es1);
    E1[gi0 + 1] = expf(ed1);   E2[gi0 + 1] = expf(0.2f * ed1);
  }

  const float m0 = mask[gi0], m1 = mask[gi0 + 1];
  const int b = gi0 >> 11, i = gi0 & 2047;
  const int ib = i >> 3, io = i & 7;
#pragma unroll
  for (int dd = 0; dd < 4; ++dd) {
    const int d = dg + 16 * dd;
    const uint32 lo = f2bf(h0[dd] * m0);
    const uint32 hi = f2bf(h1[dd] * m1);
    *(uint32*)(hTt + ((size_t)b << 17) + (ib << 9) + (d << 3) + io) = lo | (hi << 16);
  }
}

// ---------------------------------------------------------------------------
// K3: single streaming read of adj (128MB). (unchanged, measured ~26us)
// ---------------------------------------------------------------------------
__global__ __launch_bounds__(256) void k3_stats(
    const int* __restrict__ adj,
    const float* __restrict__ E1, const float* __restrict__ E2,
    const float* __restrict__ ET, const float* __restrict__ G,
    uint32* __restrict__ bitA, uint32* __restrict__ bitB,
    uint32* __restrict__ PP) {
  const int w = threadIdx.x >> 6, lane = threadIdx.x & 63;
  const int gi = blockIdx.x * 4 + w;
  const int b = gi >> 11, i = gi & 2047;
  const float eti = ET[gi];
  const int4* arow = (const int4*)(adj + (size_t)gi * 2048);
  const float4* e1p = (const float4*)(E1 + b * 2048);
  const float4* e2p = (const float4*)(E2 + b * 2048);
  float s1 = 0.f, s2 = 0.f;
#pragma unroll
  for (int jc = 0; jc < 8; ++jc) {
    const int idx = jc * 64 + lane;
    const int4 av = arow[idx];
    const float4 e1 = e1p[idx];
    const float4 e2 = e2p[idx];
    const bool m0 = (av.x == 1), m1b = (av.y == 1), m2 = (av.z == 1), m3 = (av.w == 1);
    const bool q0 = (e1.x > eti), q1 = (e1.y > eti), q2 = (e1.z > eti), q3 = (e1.w > eti);
    s1 += (m0 && q0) ? e1.x : 0.f;   s2 += (m0 && !q0) ? e2.x : 0.f;
    s1 += (m1b && q1) ? e1.y : 0.f;  s2 += (m1b && !q1) ? e2.y : 0.f;
    s1 += (m2 && q2) ? e1.z : 0.f;   s2 += (m2 && !q2) ? e2.z : 0.f;
    s1 += (m3 && q3) ? e1.w : 0.f;   s2 += (m3 && !q3) ? e2.w : 0.f;
    const u64 b0 = __ballot(m0), b1 = __ballot(m1b), b2 = __ballot(m2), b3 = __ballot(m3);
    if (lane < 4) {
      const u64 v = (lane == 0) ? b0 : (lane == 1) ? b1 : (lane == 2) ? b2 : b3;
      const size_t off = (size_t)(b * 32 + jc * 4 + lane) * 2048 + i;
      bitA[off] = (uint32)v;
      bitB[off] = (uint32)(v >> 32);
    }
  }
#pragma unroll
  for (int m = 1; m < 64; m <<= 1) {
    s1 += __shfl_xor(s1, m, 64);
    s2 += __shfl_xor(s2, m, 64);
  }
  if (lane == 0) {
    const float g = G[gi];
    const bool ok = (s1 + s2) > 0.f;
    const float p1 = ok ? 1.f / (s1 + s2 / g) : 0.f;
    const float p2 = ok ? 1.f / (s1 * g + s2) : 0.f;
    PP[gi] = (uint32)f2bf(p1) | ((uint32)f2bf(p2) << 16);
  }
}

// ---------------------------------------------------------------------------
// K4 v10 (= v9 + pinned B-prefetch): pe = bit ? max(P1*E1, P2*E2) : 0.
//   v9 proved the A-side LDS hoist (74.2 -> 67.6). The remaining per-kt
//   global loads are the 4 B-fragments; the compiler sinks source-level
//   prefetch down to its use (round 9: VGPR=40), exposing L2 latency each
//   kt. Fix: issue B(kt+1) loads at the TOP of the iteration and pin them
//   with __builtin_amdgcn_sched_barrier(0) -- nothing may cross, so the
//   loads stay issued a full iteration (~200cy of pe-gen+ds_read+MFMA)
//   before their use at kt+1. __launch_bounds__(256,4): 128-VGPR budget
//   for the 16 extra in-flight B-regs (occupancy is LDS-capped at 3
//   blocks/CU regardless).
// ---------------------------------------------------------------------------
__global__ __launch_bounds__(256, 4) void k4_fused(
    const unsigned short* __restrict__ hTt,
    const uint32* __restrict__ bitA, const uint32* __restrict__ bitB,
    const float* __restrict__ E1, const float* __restrict__ E2,
    const uint32* __restrict__ PP, float* __restrict__ out) {
  __shared__ __align__(16) char raw[41024];
  uint32* bitsL = (uint32*)raw;            // [4][2052] (+4 pad: bank spread)
  uint32* ppL = (uint32*)(raw + 32832);    // [2048]
  float* sa = (float*)raw;                 // reused post-loop: [3][16][68]

  const int t = threadIdx.x;
  const int w = t >> 6, l = t & 63;   // w = K-quarter
  const int bid = blockIdx.x;
  const int b = bid & 7;
  const int jt = bid >> 3;            // 0..127
  const int J0 = jt * 16;
  const int jj = J0 + (l & 15);
  const int kg = l >> 4;

  const float rE1 = E1[b * 2048 + jj];
  const float rE2 = E2[b * 2048 + jj];
  const int widxBase = (J0 >> 8) << 2;        // jj>>8 uniform in tile
  const int sh = (jj >> 2) & 63;              // plane uniform in tile
  const uint32 maskbit = 1u << (sh & 31);
  const uint32* plane = (sh >= 32) ? bitB : bitA;
  const uint32* rowBase = plane + (size_t)(b * 32 + widxBase) * 2048;
  const uint32* PPb = PP + b * 2048;
  const unsigned short* hTtb = hTt + ((size_t)b << 17);

  // ---- cooperative stage: 4 bit-rows (full i range) + PP, coalesced ----
  for (int idx = t; idx < 2048; idx += 256) {
    const int r = idx >> 9, c = (idx & 511) << 2;
    *(uint4*)&bitsL[r * 2052 + c] = *(const uint4*)(rowBase + (size_t)r * 2048 + c);
  }
  for (int idx = t; idx < 512; idx += 256)
    *(uint4*)&ppL[idx << 2] = *(const uint4*)(PPb + (idx << 2));
  __syncthreads();

  f32x4 acc[4] = {};
  const int arow = (l & 3) * 2052;    // lane's bit-row: widxBase + (jj&3)
  const int lane15_3 = (l & 15) << 3;

  // ---- B-side prologue (kt = 0) ----
  size_t bb = ((size_t)((w * 512) >> 3) + kg) << 9;
  bf16x8 bv0 = *(const bf16x8*)(hTtb + bb + lane15_3);
  bf16x8 bv1 = *(const bf16x8*)(hTtb + bb + lane15_3 + 128);
  bf16x8 bv2 = *(const bf16x8*)(hTtb + bb + lane15_3 + 256);
  bf16x8 bv3 = *(const bf16x8*)(hTtb + bb + lane15_3 + 384);

#pragma unroll
  for (int kt = 0; kt < 16; ++kt) {
    // B-side prefetch kt+1, issued FIRST (branchless wrap on last iter)
    const int i0n = w * 512 + ((kt + 1) & 15) * 32;
    const size_t nbb = ((size_t)(i0n >> 3) + kg) << 9;
    const bf16x8 nv0 = *(const bf16x8*)(hTtb + nbb + lane15_3);
    const bf16x8 nv1 = *(const bf16x8*)(hTtb + nbb + lane15_3 + 128);
    const bf16x8 nv2 = *(const bf16x8*)(hTtb + nbb + lane15_3 + 256);
    const bf16x8 nv3 = *(const bf16x8*)(hTtb + nbb + lane15_3 + 384);
    // pin: the loads above may not sink below this point; consumed next kt
    __builtin_amdgcn_sched_barrier(0);

    const int ibi = w * 512 + kt * 32 + kg * 8;

    // A-side from LDS (ds_read_b128 x4; 2-way bank max = free)
    const uint4 bq0 = *(const uint4*)&bitsL[arow + ibi];
    const uint4 bq1 = *(const uint4*)&bitsL[arow + ibi + 4];
    const uint4 pq0 = *(const uint4*)&ppL[ibi];
    const uint4 pq1 = *(const uint4*)&ppL[ibi + 4];

    auto pv = [&](uint32 dw, uint32 pp) -> uint32 {
      const float p1f = __builtin_bit_cast(float, pp << 16);
      const float p2f = __builtin_bit_cast(float, pp & 0xFFFF0000u);
      const float v = fmaxf(p1f * rE1, p2f * rE2);
      return (dw & maskbit) ? __builtin_bit_cast(uint32, v) : 0u;
    };
    uint32 pe[8];
    pe[0] = pv(bq0.x, pq0.x);
    pe[1] = pv(bq0.y, pq0.y);
    pe[2] = pv(bq0.z, pq0.z);
    pe[3] = pv(bq0.w, pq0.w);
    pe[4] = pv(bq1.x, pq1.x);
    pe[5] = pv(bq1.y, pq1.y);
    pe[6] = pv(bq1.z, pq1.z);
    pe[7] = pv(bq1.w, pq1.w);

    union { uint32 u4[4]; bf16x8 v; } af;
#pragma unroll
    for (int e = 0; e < 4; ++e)  // truncating bf16 pair-pack
      af.u4[e] = (pe[2 * e + 1] & 0xFFFF0000u) | (pe[2 * e] >> 16);

    acc[0] = __builtin_amdgcn_mfma_f32_16x16x32_bf16(af.v, bv0, acc[0], 0, 0, 0);
    acc[1] = __builtin_amdgcn_mfma_f32_16x16x32_bf16(af.v, bv1, acc[1], 0, 0, 0);
    acc[2] = __builtin_amdgcn_mfma_f32_16x16x32_bf16(af.v, bv2, acc[2], 0, 0, 0);
    acc[3] = __builtin_amdgcn_mfma_f32_16x16x32_bf16(af.v, bv3, acc[3], 0, 0, 0);

    bv0 = nv0; bv1 = nv1; bv2 = nv2; bv3 = nv3;
  }

  // ---- epilogue: reuse LDS for cross-wave reduce + ELU ----
  __syncthreads();  // all waves done reading bitsL/ppL
  if (w > 0) {
#pragma unroll
    for (int dt = 0; dt < 4; ++dt)
#pragma unroll
      for (int r = 0; r < 4; ++r)
        sa[(w - 1) * 1088 + ((l >> 4) * 4 + r) * 68 + dt * 16 + (l & 15)] = acc[dt][r];
  }
  __syncthreads();
  if (w == 0) {
    float* outb = out + ((size_t)b << 17);
#pragma unroll
    for (int dt = 0; dt < 4; ++dt) {
#pragma unroll
      for (int r = 0; r < 4; ++r) {
        const int jrow = (l >> 4) * 4 + r;
        const int d = dt * 16 + (l & 15);
        float s = acc[dt][r] + sa[jrow * 68 + d] + sa[1088 + jrow * 68 + d] +
                  sa[2176 + jrow * 68 + d];
        s = s > 0.f ? s : expm1f(s);
        outb[(size_t)(J0 + jrow) * 64 + d] = s;
      }
    }
  }
}

extern "C" void kernel_launch(void* const* d_in, const int* in_sizes, int n_in,
                              void* d_out, int out_size, void* d_ws, size_t ws_size,
                              hipStream_t stream) {
  const float* X = (const float*)d_in[0];     // [8,2048,128] f32
  const int* adj = (const int*)d_in[1];       // [8,2048,2048] i32
  const float* mask = (const float*)d_in[2];  // [8,2048] f32
  const float* W = (const float*)d_in[3];     // [128,64] f32
  const float* A = (const float*)d_in[4];     // [128,1] f32
  float* out = (float*)d_out;                 // [8,2048,64] f32
  char* ws = (char*)d_ws;

  unsigned short* hTt = (unsigned short*)(ws);  // 2 MB (k-blocked)
  float* E1 = (float*)(ws + 2097152);           // 64 KB each
  float* E2 = (float*)(ws + 2162688);
  float* ET = (float*)(ws + 2228224);
  float* G  = (float*)(ws + 2293760);
  uint32* PP = (uint32*)(ws + 2359296);         // 64 KB
  uint32* bitA = (uint32*)(ws + 2424832);       // 2 MB
  uint32* bitB = (uint32*)(ws + 4521984);       // 2 MB (ends 6619136)

  hipLaunchKernelGGL(k1_h_e, dim3(512), dim3(256), 0, stream, X, W, A, mask, hTt, E1, E2, ET, G);
  hipLaunchKernelGGL(k3_stats, dim3(4096), dim3(256), 0, stream, adj, E1, E2, ET, G, bitA, bitB, PP);
  hipLaunchKernelGGL(k4_fused, dim3(1024), dim3(256), 0, stream, hTt, bitA, bitB, E1, E2, PP, out);
}

// Round 18
// 62.245 us; speedup vs baseline: 1.3845x; 1.0302x over previous
//
#include <hip/hip_runtime.h>
#include <stdint.h>

typedef unsigned int uint32;
typedef unsigned long long u64;
typedef short bf16x8 __attribute__((ext_vector_type(8)));
typedef float f32x4 __attribute__((ext_vector_type(4)));

// fp32 -> bf16 bits, round-to-nearest-even
__device__ __forceinline__ unsigned short f2bf(float f) {
  uint32 u = __builtin_bit_cast(uint32, f);
  u += 0x7FFFu + ((u >> 16) & 1u);
  return (unsigned short)(u >> 16);
}

// ---------------------------------------------------------------------------
// K1: h = X*W (16384x128 @ 128x64), e_src/e_dst = h.a, store
//   hTt : bf16, k-blocked layout [B][i>>3][d][i&7]  (256KB/batch)
//   E1 = exp(e_dst), E2 = exp(0.2 e_dst)   (per j)
//   ET = exp(-e_src), G = exp(0.8 e_src)   (per i)
// ---------------------------------------------------------------------------
__global__ __launch_bounds__(256) void k1_h_e(
    const float* __restrict__ X, const float* __restrict__ W,
    const float* __restrict__ A, const float* __restrict__ mask,
    unsigned short* __restrict__ hTt,
    float* __restrict__ E1, float* __restrict__ E2,
    float* __restrict__ ET, float* __restrict__ G) {
  __shared__ float WT[64][132];
  const int t = threadIdx.x;
  for (int idx = t; idx < 128 * 64; idx += 256) {
    int k = idx >> 6, d = idx & 63;
    WT[d][k] = W[idx];
  }
  __syncthreads();

  const int dg = t & 15;
  const int rp = t >> 4;
  const int gi0 = blockIdx.x * 32 + rp * 2;

  float a1[4], a2[4];
#pragma unroll
  for (int dd = 0; dd < 4; ++dd) {
    a1[dd] = A[dg + 16 * dd];
    a2[dd] = A[64 + dg + 16 * dd];
  }

  const float4* x0 = (const float4*)(X + (size_t)gi0 * 128);
  const float4* x1 = (const float4*)(X + (size_t)(gi0 + 1) * 128);
  float h0[4] = {0.f, 0.f, 0.f, 0.f}, h1[4] = {0.f, 0.f, 0.f, 0.f};
#pragma unroll 4
  for (int kq = 0; kq < 32; ++kq) {
    const float4 xa = x0[kq], xb = x1[kq];
#pragma unroll
    for (int dd = 0; dd < 4; ++dd) {
      const float4 w4 = *(const float4*)(&WT[dg + 16 * dd][kq * 4]);
      h0[dd] += xa.x * w4.x + xa.y * w4.y + xa.z * w4.z + xa.w * w4.w;
      h1[dd] += xb.x * w4.x + xb.y * w4.y + xb.z * w4.z + xb.w * w4.w;
    }
  }

  float es0 = 0.f, ed0 = 0.f, es1 = 0.f, ed1 = 0.f;
#pragma unroll
  for (int dd = 0; dd < 4; ++dd) {
    es0 += h0[dd] * a1[dd]; ed0 += h0[dd] * a2[dd];
    es1 += h1[dd] * a1[dd]; ed1 += h1[dd] * a2[dd];
  }
#pragma unroll
  for (int m = 1; m < 16; m <<= 1) {
    es0 += __shfl_xor(es0, m, 64);
    ed0 += __shfl_xor(ed0, m, 64);
    es1 += __shfl_xor(es1, m, 64);
    ed1 += __shfl_xor(ed1, m, 64);
  }
  if (dg == 0) {
    ET[gi0] = expf(-es0);      G[gi0] = expf(0.8f * es0);
    E1[gi0] = expf(ed0);       E2[gi0] = expf(0.2f * ed0);
    ET[gi0 + 1] = expf(-es1);  G[gi0 + 1] = expf(0.8f * es1);
    E1[gi0 + 1] = expf(ed1);   E2[gi0 + 1] = expf(0.2f * ed1);
  }

  const float m0 = mask[gi0], m1 = mask[gi0 + 1];
  const int b = gi0 >> 11, i = gi0 & 2047;
  const int ib = i >> 3, io = i & 7;
#pragma unroll
  for (int dd = 0; dd < 4; ++dd) {
    const int d = dg + 16 * dd;
    const uint32 lo = f2bf(h0[dd] * m0);
    const uint32 hi = f2bf(h1[dd] * m1);
    *(uint32*)(hTt + ((size_t)b << 17) + (ib << 9) + (d << 3) + io) = lo | (hi << 16);
  }
}

// ---------------------------------------------------------------------------
// K3: single streaming read of adj (128MB). (unchanged, measured ~26us)
// ---------------------------------------------------------------------------
__global__ __launch_bounds__(256) void k3_stats(
    const int* __restrict__ adj,
    const float* __restrict__ E1, const float* __restrict__ E2,
    const float* __restrict__ ET, const float* __restrict__ G,
    uint32* __restrict__ bitA, uint32* __restrict__ bitB,
    uint32* __restrict__ PP) {
  const int w = threadIdx.x >> 6, lane = threadIdx.x & 63;
  const int gi = blockIdx.x * 4 + w;
  const int b = gi >> 11, i = gi & 2047;
  const float eti = ET[gi];
  const int4* arow = (const int4*)(adj + (size_t)gi * 2048);
  const float4* e1p = (const float4*)(E1 + b * 2048);
  const float4* e2p = (const float4*)(E2 + b * 2048);
  float s1 = 0.f, s2 = 0.f;
#pragma unroll
  for (int jc = 0; jc < 8; ++jc) {
    const int idx = jc * 64 + lane;
    const int4 av = arow[idx];
    const float4 e1 = e1p[idx];
    const float4 e2 = e2p[idx];
    const bool m0 = (av.x == 1), m1b = (av.y == 1), m2 = (av.z == 1), m3 = (av.w == 1);
    const bool q0 = (e1.x > eti), q1 = (e1.y > eti), q2 = (e1.z > eti), q3 = (e1.w > eti);
    s1 += (m0 && q0) ? e1.x : 0.f;   s2 += (m0 && !q0) ? e2.x : 0.f;
    s1 += (m1b && q1) ? e1.y : 0.f;  s2 += (m1b && !q1) ? e2.y : 0.f;
    s1 += (m2 && q2) ? e1.z : 0.f;   s2 += (m2 && !q2) ? e2.z : 0.f;
    s1 += (m3 && q3) ? e1.w : 0.f;   s2 += (m3 && !q3) ? e2.w : 0.f;
    const u64 b0 = __ballot(m0), b1 = __ballot(m1b), b2 = __ballot(m2), b3 = __ballot(m3);
    if (lane < 4) {
      const u64 v = (lane == 0) ? b0 : (lane == 1) ? b1 : (lane == 2) ? b2 : b3;
      const size_t off = (size_t)(b * 32 + jc * 4 + lane) * 2048 + i;
      bitA[off] = (uint32)v;
      bitB[off] = (uint32)(v >> 32);
    }
  }
#pragma unroll
  for (int m = 1; m < 64; m <<= 1) {
    s1 += __shfl_xor(s1, m, 64);
    s2 += __shfl_xor(s2, m, 64);
  }
  if (lane == 0) {
    const float g = G[gi];
    const bool ok = (s1 + s2) > 0.f;
    const float p1 = ok ? 1.f / (s1 + s2 / g) : 0.f;
    const float p2 = ok ? 1.f / (s1 * g + s2) : 0.f;
    PP[gi] = (uint32)f2bf(p1) | ((uint32)f2bf(p2) << 16);
  }
}

// ---------------------------------------------------------------------------
// K4 v11 (j-tile 32, shared B): pe = bit ? max(P1*E1, P2*E2) : 0.
//   B-fragments depend only on (i,d) -> each wave computes TWO 16-j subtiles
//   (jja, jjb=jja+16) from the SAME 4 B-registers: 8 MFMAs/kt, acc x2.
//   Halves the redundant per-XCD L2 B-read volume (32 -> 16 MB) and the
//   A-stage traffic. Invariants (proven): both halves share the same 4
//   staged bit-rows (jj&3, jj>>8 equal), one plane (32-aligned J0 =>
//   (J0>>2)%32 <= 24), half-1 mask bit = half-0 << 4. LDS stage unchanged.
//   Keeps v10's pinned B-prefetch (sched_barrier) + LDS A-side.
// ---------------------------------------------------------------------------
__global__ __launch_bounds__(256, 2) void k4_fused(
    const unsigned short* __restrict__ hTt,
    const uint32* __restrict__ bitA, const uint32* __restrict__ bitB,
    const float* __restrict__ E1, const float* __restrict__ E2,
    const uint32* __restrict__ PP, float* __restrict__ out) {
  __shared__ __align__(16) char raw[41024];
  uint32* bitsL = (uint32*)raw;            // [4][2052] (+4 pad: bank spread)
  uint32* ppL = (uint32*)(raw + 32832);    // [2048]
  float* sa = (float*)raw;                 // reused post-loop: [3][32][68]

  const int t = threadIdx.x;
  const int w = t >> 6, l = t & 63;   // w = K-quarter
  const int bid = blockIdx.x;
  const int b = bid & 7;
  const int jt = bid >> 3;            // 0..63
  const int J0 = jt * 32;
  const int jja = J0 + (l & 15);
  const int jjb = jja + 16;
  const int kg = l >> 4;

  const float rE1a = E1[b * 2048 + jja];
  const float rE2a = E2[b * 2048 + jja];
  const float rE1b = E1[b * 2048 + jjb];
  const float rE2b = E2[b * 2048 + jjb];
  const int widxBase = (J0 >> 8) << 2;        // uniform for both halves
  const int sh = (jja >> 2) & 63;             // plane uniform for 32-j tile
  const uint32 mbA = 1u << (sh & 31);
  const uint32 mbB = 1u << ((sh & 31) + 4);   // (sh&31)+4 <= 31 for 32-aligned J0
  const uint32* plane = (sh >= 32) ? bitB : bitA;
  const uint32* rowBase = plane + (size_t)(b * 32 + widxBase) * 2048;
  const uint32* PPb = PP + b * 2048;
  const unsigned short* hTtb = hTt + ((size_t)b << 17);

  // ---- cooperative stage: 4 bit-rows (full i range) + PP, coalesced ----
  for (int idx = t; idx < 2048; idx += 256) {
    const int r = idx >> 9, c = (idx & 511) << 2;
    *(uint4*)&bitsL[r * 2052 + c] = *(const uint4*)(rowBase + (size_t)r * 2048 + c);
  }
  for (int idx = t; idx < 512; idx += 256)
    *(uint4*)&ppL[idx << 2] = *(const uint4*)(PPb + (idx << 2));
  __syncthreads();

  f32x4 accA[4] = {}, accB[4] = {};
  const int arow = (l & 3) * 2052;    // lane's bit-row (same both halves)
  const int lane15_3 = (l & 15) << 3;

  // ---- B-side prologue (kt = 0) ----
  size_t bb = ((size_t)((w * 512) >> 3) + kg) << 9;
  bf16x8 bv0 = *(const bf16x8*)(hTtb + bb + lane15_3);
  bf16x8 bv1 = *(const bf16x8*)(hTtb + bb + lane15_3 + 128);
  bf16x8 bv2 = *(const bf16x8*)(hTtb + bb + lane15_3 + 256);
  bf16x8 bv3 = *(const bf16x8*)(hTtb + bb + lane15_3 + 384);

#pragma unroll
  for (int kt = 0; kt < 16; ++kt) {
    // B-side prefetch kt+1, issued FIRST (branchless wrap on last iter)
    const int i0n = w * 512 + ((kt + 1) & 15) * 32;
    const size_t nbb = ((size_t)(i0n >> 3) + kg) << 9;
    const bf16x8 nv0 = *(const bf16x8*)(hTtb + nbb + lane15_3);
    const bf16x8 nv1 = *(const bf16x8*)(hTtb + nbb + lane15_3 + 128);
    const bf16x8 nv2 = *(const bf16x8*)(hTtb + nbb + lane15_3 + 256);
    const bf16x8 nv3 = *(const bf16x8*)(hTtb + nbb + lane15_3 + 384);
    __builtin_amdgcn_sched_barrier(0);  // loads may not sink below

    const int ibi = w * 512 + kt * 32 + kg * 8;

    // A-side from LDS (ds_read_b128 x4; shared by both halves)
    const uint4 bq0 = *(const uint4*)&bitsL[arow + ibi];
    const uint4 bq1 = *(const uint4*)&bitsL[arow + ibi + 4];
    const uint4 pq0 = *(const uint4*)&ppL[ibi];
    const uint4 pq1 = *(const uint4*)&ppL[ibi + 4];

    // pe for both halves; shared P1/P2 unpack per i-element
    uint32 peA[8], peB[8];
    auto pv2 = [&](uint32 dw, uint32 pp, int e) {
      const float p1f = __builtin_bit_cast(float, pp << 16);
      const float p2f = __builtin_bit_cast(float, pp & 0xFFFF0000u);
      const float va = fmaxf(p1f * rE1a, p2f * rE2a);
      const float vb = fmaxf(p1f * rE1b, p2f * rE2b);
      peA[e] = (dw & mbA) ? __builtin_bit_cast(uint32, va) : 0u;
      peB[e] = (dw & mbB) ? __builtin_bit_cast(uint32, vb) : 0u;
    };
    pv2(bq0.x, pq0.x, 0);
    pv2(bq0.y, pq0.y, 1);
    pv2(bq0.z, pq0.z, 2);
    pv2(bq0.w, pq0.w, 3);
    pv2(bq1.x, pq1.x, 4);
    pv2(bq1.y, pq1.y, 5);
    pv2(bq1.z, pq1.z, 6);
    pv2(bq1.w, pq1.w, 7);

    union { uint32 u4[4]; bf16x8 v; } afA, afB;
#pragma unroll
    for (int e = 0; e < 4; ++e) {  // truncating bf16 pair-pack
      afA.u4[e] = (peA[2 * e + 1] & 0xFFFF0000u) | (peA[2 * e] >> 16);
      afB.u4[e] = (peB[2 * e + 1] & 0xFFFF0000u) | (peB[2 * e] >> 16);
    }

    accA[0] = __builtin_amdgcn_mfma_f32_16x16x32_bf16(afA.v, bv0, accA[0], 0, 0, 0);
    accA[1] = __builtin_amdgcn_mfma_f32_16x16x32_bf16(afA.v, bv1, accA[1], 0, 0, 0);
    accA[2] = __builtin_amdgcn_mfma_f32_16x16x32_bf16(afA.v, bv2, accA[2], 0, 0, 0);
    accA[3] = __builtin_amdgcn_mfma_f32_16x16x32_bf16(afA.v, bv3, accA[3], 0, 0, 0);
    accB[0] = __builtin_amdgcn_mfma_f32_16x16x32_bf16(afB.v, bv0, accB[0], 0, 0, 0);
    accB[1] = __builtin_amdgcn_mfma_f32_16x16x32_bf16(afB.v, bv1, accB[1], 0, 0, 0);
    accB[2] = __builtin_amdgcn_mfma_f32_16x16x32_bf16(afB.v, bv2, accB[2], 0, 0, 0);
    accB[3] = __builtin_amdgcn_mfma_f32_16x16x32_bf16(afB.v, bv3, accB[3], 0, 0, 0);

    bv0 = nv0; bv1 = nv1; bv2 = nv2; bv3 = nv3;
  }

  // ---- epilogue: reuse LDS for cross-wave reduce + ELU (32 j rows) ----
  __syncthreads();  // all waves done reading bitsL/ppL
  if (w > 0) {
#pragma unroll
    for (int dt = 0; dt < 4; ++dt)
#pragma unroll
      for (int r = 0; r < 4; ++r) {
        const int jrow = (l >> 4) * 4 + r;
        sa[(w - 1) * 2176 + jrow * 68 + dt * 16 + (l & 15)] = accA[dt][r];
        sa[(w - 1) * 2176 + (16 + jrow) * 68 + dt * 16 + (l & 15)] = accB[dt][r];
      }
  }
  __syncthreads();
  if (w == 0) {
    float* outb = out + ((size_t)b << 17);
#pragma unroll
    for (int dt = 0; dt < 4; ++dt) {
#pragma unroll
      for (int r = 0; r < 4; ++r) {
        const int jrow = (l >> 4) * 4 + r;
        const int d = dt * 16 + (l & 15);
        float s = accA[dt][r] + sa[jrow * 68 + d] + sa[2176 + jrow * 68 + d] +
                  sa[4352 + jrow * 68 + d];
        s = s > 0.f ? s : expm1f(s);
        outb[(size_t)(J0 + jrow) * 64 + d] = s;
        float s2 = accB[dt][r] + sa[(16 + jrow) * 68 + d] +
                   sa[2176 + (16 + jrow) * 68 + d] + sa[4352 + (16 + jrow) * 68 + d];
        s2 = s2 > 0.f ? s2 : expm1f(s2);
        outb[(size_t)(J0 + 16 + jrow) * 64 + d] = s2;
      }
    }
  }
}

extern "C" void kernel_launch(void* const* d_in, const int* in_sizes, int n_in,
                              void* d_out, int out_size, void* d_ws, size_t ws_size,
                              hipStream_t stream) {
  const float* X = (const float*)d_in[0];     // [8,2048,128] f32
  const int* adj = (const int*)d_in[1];       // [8,2048,2048] i32
  const float* mask = (const float*)d_in[2];  // [8,2048] f32
  const float* W = (const float*)d_in[3];     // [128,64] f32
  const float* A = (const float*)d_in[4];     // [128,1] f32
  float* out = (float*)d_out;                 // [8,2048,64] f32
  char* ws = (char*)d_ws;

  unsigned short* hTt = (unsigned short*)(ws);  // 2 MB (k-blocked)
  float* E1 = (float*)(ws + 2097152);           // 64 KB each
  float* E2 = (float*)(ws + 2162688);
  float* ET = (float*)(ws + 2228224);
  float* G  = (float*)(ws + 2293760);
  uint32* PP = (uint32*)(ws + 2359296);         // 64 KB
  uint32* bitA = (uint32*)(ws + 2424832);       // 2 MB
  uint32* bitB = (uint32*)(ws + 4521984);       // 2 MB (ends 6619136)

  hipLaunchKernelGGL(k1_h_e, dim3(512), dim3(256), 0, stream, X, W, A, mask, hTt, E1, E2, ET, G);
  hipLaunchKernelGGL(k3_stats, dim3(4096), dim3(256), 0, stream, adj, E1, E2, ET, G, bitA, bitB, PP);
  hipLaunchKernelGGL(k4_fused, dim3(512), dim3(256), 0, stream, hTt, bitA, bitB, E1, E2, PP, out);
}